// Round 10
// baseline (480.397 us; speedup 1.0000x reference)
//
#include <hip/hip_runtime.h>

#define LN_EPS 1e-5f

typedef __attribute__((ext_vector_type(8))) short bf16x8;
typedef __attribute__((ext_vector_type(8))) short s16x8;
typedef __attribute__((ext_vector_type(4))) float f32x4;

__device__ __forceinline__ unsigned short f2bf(float f){
  unsigned u = __builtin_bit_cast(unsigned, f);
  u = (u + 0x7fffu + ((u >> 16) & 1u)) >> 16;
  return (unsigned short)u;
}
__device__ __forceinline__ float bf2f(unsigned short h){
  unsigned u = ((unsigned)h) << 16;
  return __builtin_bit_cast(float, u);
}
__device__ __forceinline__ void gll16(const void* g, void* l){
  __builtin_amdgcn_global_load_lds(
      (const __attribute__((address_space(1))) unsigned int*)(g),
      (__attribute__((address_space(3))) unsigned int*)(l), 16, 0, 0);
}

// ---------------------------------------------------------------------------
// Kernel 1: k_pre. bid<480: cond LN + K/V projection. bid>=480: WqT prep
// (256 wide blocks, no tail). WqT[n][d] = bf16(Wq[d][n]), PLAIN layout
// (B-operand is now consumed directly from L2, no swizzle needed).
// ---------------------------------------------------------------------------
__global__ void k_pre(const float* __restrict__ Wq, unsigned short* __restrict__ WqT,
                      const float* __restrict__ cond, const int* __restrict__ idx,
                      const float* __restrict__ tg, const float* __restrict__ tb,
                      const float* __restrict__ Wk, const float* __restrict__ bk,
                      const float* __restrict__ Wv, const float* __restrict__ bv,
                      float* __restrict__ kbuf, float* __restrict__ vbuf)
{
  __shared__ float cn[16][768];
  const int bid = blockIdx.x, tid = threadIdx.x;

  if(bid >= 480){
    const int pb = bid - 480;                 // 0..255
    const int n  = pb*2 + (tid & 1);
    const int d  = (tid >> 1) * 4;
    ushort4 pk;
    pk.x = f2bf(Wq[(size_t)(d+0)*512 + n]);
    pk.y = f2bf(Wq[(size_t)(d+1)*512 + n]);
    pk.z = f2bf(Wq[(size_t)(d+2)*512 + n]);
    pk.w = f2bf(Wq[(size_t)(d+3)*512 + n]);
    *(ushort4*)(WqT + (size_t)n*512 + d) = pk;
    return;
  }

  // condkv role (validated): dc = bid&3, nc = (bid>>2)%5, bc = (bid>>2)/5
  const int dc = bid & 3;
  const int r2 = bid >> 2;
  const int nc = r2 % 5;
  const int bc = r2 / 5;
  const int b = idx[bc];
  const int n0 = nc * 16;
  int nrows = 77 - n0; if(nrows > 16) nrows = 16;
  const int w = tid >> 6, lane = tid & 63;

  for(int r = w; r < nrows; r += 4){
    const float* src = cond + ((size_t)b * 77 + n0 + r) * 768;
    float vals[12]; float s1 = 0.f, s2 = 0.f;
    #pragma unroll
    for(int i=0;i<12;i++){ float x = src[lane + i*64]; vals[i]=x; s1+=x; s2+=x*x; }
    #pragma unroll
    for(int off=1; off<64; off<<=1){ s1 += __shfl_xor(s1, off); s2 += __shfl_xor(s2, off); }
    const float mu  = s1 * (1.f/768.f);
    const float var = s2 * (1.f/768.f) - mu*mu;
    const float rs  = rsqrtf(var + LN_EPS);
    #pragma unroll
    for(int i=0;i<12;i++){ const int c2 = lane + i*64; cn[r][c2] = (vals[i]-mu)*rs*tg[c2] + tb[c2]; }
  }
  __syncthreads();

  const int dq = tid & 63;
  const int part = tid >> 6;
  const float* W    = (dc < 2) ? Wk : Wv;
  const float* bias = (dc < 2) ? bk : bv;
  float* obuf       = (dc < 2) ? kbuf : vbuf;
  const int d0 = (dc & 1) * 256 + dq * 4;

  float acc[4][4] = {};
  for(int i=0;i<768;i++){
    const float4 wv = *(const float4*)(W + (size_t)i * 512 + d0);
    #pragma unroll
    for(int j=0;j<4;j++){
      const float c = cn[part*4 + j][i];
      acc[j][0] += c * wv.x; acc[j][1] += c * wv.y;
      acc[j][2] += c * wv.z; acc[j][3] += c * wv.w;
    }
  }
  #pragma unroll
  for(int j=0;j<4;j++){
    const int r = part*4 + j, n = n0 + r;
    if(r < nrows){
      float4 o;
      o.x = acc[j][0] + bias[d0+0];
      o.y = acc[j][1] + bias[d0+1];
      o.z = acc[j][2] + bias[d0+2];
      o.w = acc[j][3] + bias[d0+3];
      *(float4*)(obuf + ((size_t)bc * 77 + n) * 512 + d0) = o;
    }
  }
}

// ---------------------------------------------------------------------------
// Kernel 2: k_mid — all independent mid-stage work in ONE launch, 40KB LDS
// (4 blocks/CU). bid<3072: LN+transpose (bf16 LDS buf). 3072..3583: copy
// role (non-cond batches). 3584..3775: ctx role (softmax K + packed context).
// ---------------------------------------------------------------------------
__global__ __launch_bounds__(256, 4)
void k_mid(const float* __restrict__ input, const int* __restrict__ idx,
           const float* __restrict__ ln_g, const float* __restrict__ ln_b,
           unsigned short* __restrict__ xT, float* __restrict__ out,
           const float* __restrict__ kbuf, const float* __restrict__ vbuf,
           unsigned short* __restrict__ ctxP)
{
  __shared__ __align__(16) char sm[40960];
  const int bid = blockIdx.x, tid = threadIdx.x;

  if(bid < 3072){
    // ---- LN + transpose role: block = 32 t x 512 d ----
    unsigned short* const buf = (unsigned short*)sm;   // [32][528] bf16 = 33792B
    float* const red1 = (float*)(sm + 33792);          // [32][4]
    float* const red2 = (float*)(sm + 34304);          // [32][4]
    float* const mu_s = (float*)(sm + 34816);          // [32]
    float* const rs_s = (float*)(sm + 34944);          // [32]
    float* const gbuf = (float*)(sm + 35072);          // [512]
    float* const bbuf = (float*)(sm + 37120);          // [512]

    const int bc = bid >> 7, tile = bid & 127;
    const int b  = idx[bc];
    const int t0 = tile * 32;
    const float* xb = input + (size_t)b * 2097152 + t0;

    *(float2*)&gbuf[tid*2] = *(const float2*)&ln_g[tid*2];
    *(float2*)&bbuf[tid*2] = *(const float2*)&ln_b[tid*2];

    const int p = tid & 7, dg = tid >> 3;
    const int w = tid >> 6, lane = tid & 63;
    float s1[4] = {0,0,0,0}, s2[4] = {0,0,0,0};
    #pragma unroll
    for(int i=0;i<16;i++){
      const int d = dg + i*32;
      const float4 x = *(const float4*)(xb + (size_t)d * 4096 + p*4);
      s1[0]+=x.x; s2[0]+=x.x*x.x;
      s1[1]+=x.y; s2[1]+=x.y*x.y;
      s1[2]+=x.z; s2[2]+=x.z*x.z;
      s1[3]+=x.w; s2[3]+=x.w*x.w;
      buf[(p*4+0)*528 + d] = f2bf(x.x);
      buf[(p*4+1)*528 + d] = f2bf(x.y);
      buf[(p*4+2)*528 + d] = f2bf(x.z);
      buf[(p*4+3)*528 + d] = f2bf(x.w);
    }
    // reduce over dg within wave (p preserved by xor 8/16/32)
    #pragma unroll
    for(int j=0;j<4;j++){
      s1[j] += __shfl_xor(s1[j], 8);  s2[j] += __shfl_xor(s2[j], 8);
      s1[j] += __shfl_xor(s1[j], 16); s2[j] += __shfl_xor(s2[j], 16);
      s1[j] += __shfl_xor(s1[j], 32); s2[j] += __shfl_xor(s2[j], 32);
    }
    if(lane < 8){
      #pragma unroll
      for(int j=0;j<4;j++){
        red1[(lane*4+j)*4 + w] = s1[j];
        red2[(lane*4+j)*4 + w] = s2[j];
      }
    }
    __syncthreads();
    if(tid < 32){
      const float a  = red1[tid*4] + red1[tid*4+1] + red1[tid*4+2] + red1[tid*4+3];
      const float c2 = red2[tid*4] + red2[tid*4+1] + red2[tid*4+2] + red2[tid*4+3];
      const float mu  = a * (1.f/512.f);
      const float var = c2 * (1.f/512.f) - mu*mu;
      mu_s[tid] = mu; rs_s[tid] = rsqrtf(var + LN_EPS);
    }
    __syncthreads();

    // apply + write coalesced, slot-swizzled xT rows (R8-validated layout)
    const int c  = tid & 7;
    const int tt = tid >> 3;
    const float mu = mu_s[tt], rs = rs_s[tt];
    const int swz = (tt >> 1) & 3;
    unsigned short* orow = xT + ((size_t)bc*4096 + t0 + tt) * 512;
    #pragma unroll
    for(int j=0;j<8;j++){
      const int d0 = c*8 + j*64;
      const s16x8 v = *(const s16x8*)(buf + tt*528 + d0);
      s16x8 o;
      #pragma unroll
      for(int e=0;e<8;e++){
        const int d = d0 + e;
        o[e] = (short)f2bf((bf2f((unsigned short)v[e]) - mu)*rs*gbuf[d] + bbuf[d]);
      }
      *(s16x8*)(orow + (d0 ^ (swz << 3))) = o;
    }
    return;
  }

  if(bid < 3584){
    // ---- copy role: 512 blocks over 8 non-cond batches ----
    const int cid = bid - 3072;
    const int nb = cid >> 6, chunk = cid & 63;
    int cnt = 0, bsel = 0;
    for(int b2 = 0; b2 < 32; ++b2){
      bool member = false;
      #pragma unroll
      for(int i2 = 0; i2 < 24; ++i2) member |= (idx[i2] == b2);
      if(!member){ if(cnt == nb) bsel = b2; ++cnt; }
    }
    const float4* s = (const float4*)(input + (size_t)bsel * 2097152) + chunk*8192;
    float4*       d = (float4*)      (out   + (size_t)bsel * 2097152) + chunk*8192;
    #pragma unroll
    for(int i = 0; i < 32; ++i) d[i*256 + tid] = s[i*256 + tid];
    return;
  }

  // ---- ctx role: softmax K over tokens, packed context ----
  {
    const int rid = bid - 3584;           // 0..191
    const int h = rid & 7, bc = rid >> 3;
    float (*kk)[64] = (float(*)[64])sm;              // 19712B
    float (*vv)[64] = (float(*)[64])(sm + 19712);    // 19712B
    float* inv_s    = (float*)(sm + 39424);          // 256B
    for(int e = tid; e < 77*64; e += 256){
      const int n = e >> 6, c = e & 63;
      kk[n][c] = kbuf[((size_t)bc * 77 + n) * 512 + h*64 + c];
      vv[n][c] = vbuf[((size_t)bc * 77 + n) * 512 + h*64 + c];
    }
    __syncthreads();
    if(tid < 64){
      float m = -1e30f;
      for(int n=0;n<77;n++) m = fmaxf(m, kk[n][tid]);
      float s = 0.f;
      for(int n=0;n<77;n++){ const float e = __expf(kk[n][tid] - m); kk[n][tid] = e; s += e; }
      inv_s[tid] = 1.f / s;
    }
    __syncthreads();
    #pragma unroll
    for(int j=0;j<16;j++){
      const int o = tid + 256*j;
      const int v = o >> 6, k2 = o & 63;
      float a = 0.f;
      for(int n=0;n<77;n++) a += kk[n][k2] * vv[n][v];
      const int pos = ((((k2>>5)*4 + (v>>4))*4 + ((k2>>3)&3))*16 + (v&15))*8 + (k2&7);
      ctxP[((size_t)(bc*8 + h)) * 4096 + pos] = f2bf(a * inv_s[k2]);
    }
  }
}

// ---------------------------------------------------------------------------
// Kernel 3: k_gemm3 v2. 128x128 MFMA GEMM; A staged via triple-buffered
// gll16 + counted vmcnt (R8-validated); B read DIRECT from L2-resident WqT
// (R6-validated) — wf loads issued BEFORE the stage so the compiler's
// pre-MFMA waitcnt leaves staging loads in flight. Fused softmax/PV/residual.
// grid (4 ntile, 768 mtile), 256 threads (4 waves, 2x2).
// ---------------------------------------------------------------------------
__global__ __launch_bounds__(256, 3)
void k_gemm3(const float* __restrict__ input, const int* __restrict__ idx,
             const unsigned short* __restrict__ xT, const unsigned short* __restrict__ WqT,
             const float* __restrict__ bq, const unsigned short* __restrict__ ctxP,
             float* __restrict__ out)
{
  __shared__ __align__(16) char smem[36864];   // 3 x A(8KB); P aliases to 36864
  unsigned short* P = (unsigned short*)smem;

  const int tid  = threadIdx.x;
  const int lane = tid & 63;
  const int w    = tid >> 6;
  const int col  = lane & 15;
  const int g    = lane >> 4;
  const int wm   = w >> 1, wn = w & 1;
  const int ntile = blockIdx.x, mtile = blockIdx.y;
  const int bc   = mtile >> 5;
  const int tt0  = (mtile & 31) * 128;
  const int b    = idx[bc];
  const int nbase = ntile * 128;
  const char* xTb = (const char*)xT + ((size_t)bc*4096 + tt0) * 1024;

  const int f0 = tid * 16;
  const int f1 = f0 + 4096;
  const int r0 = f0 >> 6, o0 = f0 & 63;
  const int r1 = f1 >> 6, o1 = f1 & 63;

  #define STAGE(ks, bi)                                                   \
  {                                                                       \
    char* dst = smem + (bi)*8192;                                         \
    gll16(xTb + (size_t)r0*1024 + (ks)*64 + o0, dst + f0);                \
    gll16(xTb + (size_t)r1*1024 + (ks)*64 + o1, dst + f1);                \
  }

  f32x4 acc[4][4] = {};

  int offA[4];
  #pragma unroll
  for(int mt=0; mt<4; ++mt){
    const int rowA = wm*64 + mt*16 + col;
    offA[mt] = rowA*64 + ((g ^ ((rowA>>1)&3)) << 4);
  }
  // B direct from global: row pointers into WqT (plain layout)
  const char* wrow[4];
  #pragma unroll
  for(int nt=0; nt<4; ++nt)
    wrow[nt] = (const char*)WqT + (size_t)(nbase + wn*64 + nt*16 + col)*1024 + g*16;

  STAGE(0, 0);
  STAGE(1, 1);

  #pragma unroll
  for(int ks=0; ks<16; ++ks){
    if(ks < 15) asm volatile("s_waitcnt vmcnt(2)" ::: "memory");
    else        asm volatile("s_waitcnt vmcnt(0)" ::: "memory");
    __builtin_amdgcn_s_barrier();

    // W frags first (so compiler's pre-MFMA wait keeps later stages in flight)
    bf16x8 bfr[4];
    #pragma unroll
    for(int nt=0; nt<4; ++nt) bfr[nt] = *(const bf16x8*)(wrow[nt] + ks*64);

    if(ks < 14) STAGE(ks+2, (ks+2)%3);

    char* cur = smem + (ks%3)*8192;
    bf16x8 af[4];
    #pragma unroll
    for(int mt=0; mt<4; ++mt) af[mt] = *(const bf16x8*)(cur + offA[mt]);
    #pragma unroll
    for(int mt=0; mt<4; ++mt)
      #pragma unroll
      for(int nt=0; nt<4; ++nt)
        acc[mt][nt] = __builtin_amdgcn_mfma_f32_16x16x32_bf16(af[mt], bfr[nt], acc[mt][nt], 0, 0, 0);
  }
  #undef STAGE
  __syncthreads();   // all waves done with staging buffers before P aliases

  // ---- bias + per-head feature softmax (wave owns one head) ----
  #pragma unroll
  for(int mt=0; mt<4; ++mt){
    #pragma unroll
    for(int nt=0; nt<4; ++nt){
      const float bqv = bq[nbase + wn*64 + nt*16 + col];
      #pragma unroll
      for(int r=0;r<4;++r) acc[mt][nt][r] += bqv;
    }
    #pragma unroll
    for(int r=0;r<4;++r){
      float m = fmaxf(fmaxf(acc[mt][0][r],acc[mt][1][r]), fmaxf(acc[mt][2][r],acc[mt][3][r]));
      m = fmaxf(m, __shfl_xor(m, 1));
      m = fmaxf(m, __shfl_xor(m, 2));
      m = fmaxf(m, __shfl_xor(m, 4));
      m = fmaxf(m, __shfl_xor(m, 8));
      float s = 0.f;
      #pragma unroll
      for(int q=0;q<4;++q){
        const float e = __expf(acc[mt][q][r] - m);
        acc[mt][q][r] = e; s += e;
      }
      s += __shfl_xor(s, 1);
      s += __shfl_xor(s, 2);
      s += __shfl_xor(s, 4);
      s += __shfl_xor(s, 8);
      const float inv = 1.f / s;
      #pragma unroll
      for(int q=0;q<4;++q) acc[mt][q][r] *= inv;
    }
  }

  // ---- P store (wave-private region) ----
  unsigned short* Pw = P + w * 64 * 72;
  #pragma unroll
  for(int mt=0; mt<4; ++mt)
    #pragma unroll
    for(int nt=0; nt<4; ++nt)
      #pragma unroll
      for(int r=0; r<4; ++r)
        Pw[(mt*16 + g*4 + r)*72 + nt*16 + col] = f2bf(acc[mt][nt][r]);

  // ---- PV: y[t][v] = sum_k P[t][k] * ctx[k][v] ----
  const int head = ntile*2 + wn;
  const unsigned short* cp = ctxP + (size_t)(bc*8 + head) * 4096;
  f32x4 y[4][4] = {};
  #pragma unroll
  for(int ks2=0; ks2<2; ++ks2){
    bf16x8 pa[4];
    #pragma unroll
    for(int mt=0; mt<4; ++mt)
      pa[mt] = *(const bf16x8*)(Pw + (mt*16 + col)*72 + ks2*32 + g*8);
    bf16x8 cv[4];
    #pragma unroll
    for(int vt=0; vt<4; ++vt)
      cv[vt] = *(const bf16x8*)(cp + (size_t)(((ks2*4 + vt)*4 + g)*16 + col) * 8);
    #pragma unroll
    for(int mt=0; mt<4; ++mt)
      #pragma unroll
      for(int vt=0; vt<4; ++vt)
        y[mt][vt] = __builtin_amdgcn_mfma_f32_16x16x32_bf16(pa[mt], cv[vt], y[mt][vt], 0, 0, 0);
  }

  // ---- residual + store (float4 along t) ----
  const float* xb = input + (size_t)b * 2097152;
  float*       ob = out   + (size_t)b * 2097152;
  #pragma unroll
  for(int mt=0; mt<4; ++mt)
    #pragma unroll
    for(int vt=0; vt<4; ++vt){
      const size_t a = (size_t)(head*64 + vt*16 + col)*4096
                     + (size_t)(tt0 + wm*64 + mt*16 + g*4);
      const float4 xr = *(const float4*)(xb + a);
      float4 o4;
      o4.x = xr.x + y[mt][vt][0];
      o4.y = xr.y + y[mt][vt][1];
      o4.z = xr.z + y[mt][vt][2];
      o4.w = xr.w + y[mt][vt][3];
      *(float4*)(ob + a) = o4;
    }
}

// ---------------------------------------------------------------------------
extern "C" void kernel_launch(void* const* d_in, const int* in_sizes, int n_in,
                              void* d_out, int out_size, void* d_ws, size_t ws_size,
                              hipStream_t stream)
{
  const float* input = (const float*)d_in[0];
  const float* cond  = (const float*)d_in[1];
  const int*   idx   = (const int*)d_in[2];
  const float* ln_g  = (const float*)d_in[3];
  const float* ln_b  = (const float*)d_in[4];
  const float* tln_g = (const float*)d_in[5];
  const float* tln_b = (const float*)d_in[6];
  const float* Wq    = (const float*)d_in[7];
  const float* bq    = (const float*)d_in[8];
  const float* Wk    = (const float*)d_in[9];
  const float* bk    = (const float*)d_in[10];
  const float* Wv    = (const float*)d_in[11];
  const float* bv    = (const float*)d_in[12];
  float* out = (float*)d_out;
  char*  ws  = (char*)d_ws;

  unsigned short* WqT  = (unsigned short*)(ws);                     // 512 KB
  unsigned short* ctxP = (unsigned short*)(ws + 524288);            // 1.5 MB
  float* kbuf = (float*)(ws + 2097152);                             // 3.61 MB
  float* vbuf = (float*)(ws + 2097152 + 3784704);                   // 3.61 MB
  unsigned short* xT = (unsigned short*)(ws + 2097152 + 2*3784704); // 96 MB

  k_pre  <<<dim3(736),    dim3(256), 0, stream>>>(Wq, WqT, cond, idx, tln_g, tln_b,
                                                  Wk, bk, Wv, bv, kbuf, vbuf);
  k_mid  <<<dim3(3776),   dim3(256), 0, stream>>>(input, idx, ln_g, ln_b, xT, out,
                                                  kbuf, vbuf, ctxP);
  k_gemm3<<<dim3(4,768),  dim3(256), 0, stream>>>(input, idx, xT, WqT, bq, ctxP, out);
}